// Round 13
// baseline (430.809 us; speedup 1.0000x reference)
//
#include <hip/hip_runtime.h>
#include <math.h>

#define NB 64       // batch
#define NS 512      // seq len
#define ND 512      // input dim
#define NH 512      // hidden
#define L2E 1.4426950408889634f

// 64-lane sum via DPP (VALU only). Total lands in lane 63.
__device__ __forceinline__ float dpp_sum64(float x) {
    x += __int_as_float(__builtin_amdgcn_update_dpp(0, __float_as_int(x), 0x111, 0xf, 0xf, true)); // row_shr:1
    x += __int_as_float(__builtin_amdgcn_update_dpp(0, __float_as_int(x), 0x112, 0xf, 0xf, true)); // row_shr:2
    x += __int_as_float(__builtin_amdgcn_update_dpp(0, __float_as_int(x), 0x114, 0xf, 0xf, true)); // row_shr:4
    x += __int_as_float(__builtin_amdgcn_update_dpp(0, __float_as_int(x), 0x118, 0xf, 0xf, true)); // row_shr:8
    x += __int_as_float(__builtin_amdgcn_update_dpp(0, __float_as_int(x), 0x142, 0xa, 0xf, true)); // row_bcast:15
    x += __int_as_float(__builtin_amdgcn_update_dpp(0, __float_as_int(x), 0x143, 0xc, 0xf, true)); // row_bcast:31
    return x;
}

__device__ __forceinline__ float bcast63(float x) {
    return __int_as_float(__builtin_amdgcn_readlane(__float_as_int(x), 63));
}
__device__ __forceinline__ float rcp_fast(float x) { return __builtin_amdgcn_rcpf(x); }
__device__ __forceinline__ float exp2_fast(float x) {
    float r;
    asm("v_exp_f32 %0, %1" : "=v"(r) : "v"(x));
    return r;
}
__device__ __forceinline__ void wg_barrier() {
    asm volatile("s_waitcnt lgkmcnt(0)\n\ts_barrier" ::: "memory");
}

// dot of an 8-float weight slice against the two h float4s
__device__ __forceinline__ float dot8s(const float* s, float4 x0, float4 x1) {
    float r = s[0] * x0.x;
    r = fmaf(s[1], x0.y, r); r = fmaf(s[2], x0.z, r); r = fmaf(s[3], x0.w, r);
    r = fmaf(s[4], x1.x, r); r = fmaf(s[5], x1.y, r); r = fmaf(s[6], x1.z, r);
    r = fmaf(s[7], x1.w, r);
    return r;
}

// permuted gather of factor row f (LDS slot s holds row 8*(s&63)+(s>>6))
#define LW(mat, f, arr)                                                       \
    {                                                                         \
        const float* M = (mat) + (f) * NH;                                    \
        arr[0] = M[kb];      arr[1] = M[kb + 8];                              \
        arr[2] = M[kb + 16]; arr[3] = M[kb + 24];                             \
        arr[4] = M[kb + 4];  arr[5] = M[kb + 12];                             \
        arr[6] = M[kb + 20]; arr[7] = M[kb + 28];                             \
    }

// one LSTM row update; coefficients pre-scaled by {-L2E,-L2E,+2L2E,-L2E}:
//   sigm -> 1/(1+2^g), tanh -> 1-2/(1+2^g)
#define GATEX(t1, t2, m3, m4, bb, cS, hS)                                     \
    {                                                                         \
        float g0 = fmaf(cw[0], (t1), fmaf(cdw[0], (t2), fmaf(cu[0], (m3), fmaf(cdu[0], (m4), bb[0])))); \
        float g1 = fmaf(cw[1], (t1), fmaf(cdw[1], (t2), fmaf(cu[1], (m3), fmaf(cdu[1], (m4), bb[1])))); \
        float g2 = fmaf(cw[2], (t1), fmaf(cdw[2], (t2), fmaf(cu[2], (m3), fmaf(cdu[2], (m4), bb[2])))); \
        float g3 = fmaf(cw[3], (t1), fmaf(cdw[3], (t2), fmaf(cu[3], (m3), fmaf(cdu[3], (m4), bb[3])))); \
        float ig = rcp_fast(1.0f + exp2_fast(g0));                            \
        float fg = rcp_fast(1.0f + exp2_fast(g1));                            \
        float gg = fmaf(-2.0f, rcp_fast(1.0f + exp2_fast(g2)), 1.0f);         \
        float og = rcp_fast(1.0f + exp2_fast(g3));                            \
        cS = fmaf(fg, cS, ig * gg);                                           \
        hS = og * fmaf(-2.0f, rcp_fast(1.0f + exp2_fast(cS * (2.0f * L2E))), 1.0f); \
    }

// ---------------------------------------------------------------------------
// Kernel A: PT[bt] as 8 x float2: {(W12@x)[g], (dW12@x)[g]} for g = 0..7
// ---------------------------------------------------------------------------
__global__ __launch_bounds__(64) void precomp_kernel(
    const float* __restrict__ x, const float* __restrict__ W12,
    const float* __restrict__ dW12, float* __restrict__ PT) {
    int bt = blockIdx.x;
    int l = threadIdx.x;
    const float4* xr = (const float4*)(x + (size_t)bt * ND);
    float4 xv0 = xr[l];
    float4 xv1 = xr[64 + l];

    float acc[16];
#pragma unroll
    for (int f = 0; f < 8; ++f) {
        const float4* w = (const float4*)(W12 + f * ND);
        float4 a = w[l], b = w[64 + l];
        float s = a.x * xv0.x;
        s = fmaf(a.y, xv0.y, s); s = fmaf(a.z, xv0.z, s); s = fmaf(a.w, xv0.w, s);
        s = fmaf(b.x, xv1.x, s); s = fmaf(b.y, xv1.y, s); s = fmaf(b.z, xv1.z, s);
        s = fmaf(b.w, xv1.w, s);
        acc[f] = s;
        const float4* dw = (const float4*)(dW12 + f * ND);
        float4 c = dw[l], d = dw[64 + l];
        float u = c.x * xv0.x;
        u = fmaf(c.y, xv0.y, u); u = fmaf(c.z, xv0.z, u); u = fmaf(c.w, xv0.w, u);
        u = fmaf(d.x, xv1.x, u); u = fmaf(d.y, xv1.y, u); u = fmaf(d.z, xv1.z, u);
        u = fmaf(d.w, xv1.w, u);
        acc[8 + f] = u;
    }
#pragma unroll
    for (int f = 0; f < 16; ++f) acc[f] = dpp_sum64(acc[f]);

    if (l == 63) {
        float2* o = (float2*)(PT + (size_t)bt * 16);
#pragma unroll
        for (int g = 0; g < 8; ++g) o[g] = make_float2(acc[g], acc[8 + g]);
    }
}

// ---------------------------------------------------------------------------
// Kernel B: FUSED producer+consumer, one 16-wave block per batch element.
// Wave g in [0,8): layer-1 recurrence, factor g only (U12/dU12 dots) +
//   W22/dW22 projections of h1(i) -> mr[(i-1)&1][2g..2g+1].
// Wave 8+g: layer-2 recurrence at s=i-2, factor g (U22/dU22 dots).
// Thread owns ONE row (8l+g); its row's m-values come from its own wave's
// reductions (readlane) -> zero cross-wave exchange for gates. 4 waves/SIMD
// (2 producer + 2 consumer at different phases) -> deep latency hiding.
// ONE lgkm-only barrier per iteration.
// ---------------------------------------------------------------------------
__global__ __launch_bounds__(1024, 4) void lstm_fused_kernel(
    const float* __restrict__ PT, const float* __restrict__ h0,
    const float* __restrict__ c0,
    const float* __restrict__ W11, const float* __restrict__ U11,
    const float* __restrict__ dW11, const float* __restrict__ dU11,
    const float* __restrict__ U12, const float* __restrict__ dU12,
    const float* __restrict__ b11, const float* __restrict__ b12,
    const float* __restrict__ W21, const float* __restrict__ U21,
    const float* __restrict__ dW21, const float* __restrict__ dU21,
    const float* __restrict__ W22, const float* __restrict__ dW22,
    const float* __restrict__ U22, const float* __restrict__ dU22,
    const float* __restrict__ b21, const float* __restrict__ b22,
    float* __restrict__ out) {
    int b = blockIdx.x;
    int tid = threadIdx.x;
    int wv = tid >> 6;              // 0..15
    int l = tid & 63;
    int g = wv & 7;                 // owned factor
    int kb = 32 * (l & 15) + (l >> 4);
    int r = 8 * l + g;              // owned row

    __shared__ float Ps[NS * 16];   // 32 KB staged P slice
    __shared__ float hb1[2][NH];    // layer-1 h (permuted slots)
    __shared__ float hb2[2][NH];    // layer-2 h
    __shared__ float mr[2][16];     // L1->L2 projection handoff

    // stage P (all 16 waves): 2048 float4 / 1024 threads = 2 iters
    {
        const float4* src = (const float4*)(PT + (size_t)b * NS * 16);
        float4* dst = (float4*)Ps;
        dst[tid] = src[tid];
        dst[tid + 1024] = src[tid + 1024];
    }

    float* hn = out + (size_t)NB * NS * NH;
    float* cn = hn + (size_t)2 * NB * NH;
    const float SQ[4] = {-L2E, -L2E, 2.0f * L2E, -L2E};

    if (wv < 8) {
        // ========================= PRODUCER (layer 1) ======================
        float wU[8], wD[8], wW[8], wV[8];
        LW(U12, g, wU)
        LW(dU12, g, wD)
        LW(W22, g, wW)
        LW(dW22, g, wV)

        float cw[4], cdw[4], cu[4], cdu[4], bb[4];
#pragma unroll
        for (int q = 0; q < 4; ++q) {
            cw[q] = W11[q * 64 + l] * SQ[q];
            cdw[q] = dW11[q * 64 + l] * SQ[q];
            cu[q] = U11[q * 64 + l] * SQ[q];
            cdu[q] = dU11[q * 64 + l] * SQ[q];
            bb[q] = (b11[q * NH + r] + b12[q * NH + r]) * SQ[q];
        }
        float hA = h0[(size_t)b * NH + r];
        float cA = c0[(size_t)b * NH + r];
        hb1[0][64 * g + l] = hA;
        wg_barrier();

        for (int i = 0; i <= NS + 1; ++i) {
            if (i <= NS) {
                float4 x0 = *(const float4*)&hb1[i & 1][4 * l];
                float4 x1 = *(const float4*)&hb1[i & 1][256 + 4 * l];
                // projections of h1(i) -> m record for step i-1
                float rW = dpp_sum64(dot8s(wW, x0, x1));
                float rV = dpp_sum64(dot8s(wV, x0, x1));
                if (i > 0 && l == 63)
                    *(float2*)&mr[(i - 1) & 1][2 * g] = make_float2(rW, rV);
                if (i < NS) {
                    float rU = dpp_sum64(dot8s(wU, x0, x1));
                    float rD = dpp_sum64(dot8s(wD, x0, x1));
                    float m3 = bcast63(rU), m4 = bcast63(rD);
                    float2 pv = *(const float2*)&Ps[i * 16 + 2 * g];
                    GATEX(pv.x, pv.y, m3, m4, bb, cA, hA)
                    hb1[(i + 1) & 1][64 * g + l] = hA;
                }
            }
            wg_barrier();
        }
        hn[(size_t)b * NH + r] = hA;
        cn[(size_t)b * NH + r] = cA;
    } else {
        // ========================= CONSUMER (layer 2) ======================
        float wU[8], wD[8];
        LW(U22, g, wU)
        LW(dU22, g, wD)

        float cw[4], cdw[4], cu[4], cdu[4], bb[4];
#pragma unroll
        for (int q = 0; q < 4; ++q) {
            cw[q] = W21[q * 64 + l] * SQ[q];
            cdw[q] = dW21[q * 64 + l] * SQ[q];
            cu[q] = U21[q * 64 + l] * SQ[q];
            cdu[q] = dU21[q * 64 + l] * SQ[q];
            bb[q] = (b21[q * NH + r] + b22[q * NH + r]) * SQ[q];
        }
        float hA = h0[(size_t)NB * NH + (size_t)b * NH + r];
        float cA = c0[(size_t)NB * NH + (size_t)b * NH + r];
        hb2[0][64 * g + l] = hA;
        wg_barrier();

        float* outb = out + (size_t)b * NS * NH;
        for (int i = 0; i <= NS + 1; ++i) {
            int s = i - 2;
            if (s >= 0) {
                float4 y0 = *(const float4*)&hb2[s & 1][4 * l];
                float4 y1 = *(const float4*)&hb2[s & 1][256 + 4 * l];
                float rU = dpp_sum64(dot8s(wU, y0, y1));
                float rD = dpp_sum64(dot8s(wD, y0, y1));
                float m5 = bcast63(rU), m6 = bcast63(rD);
                float2 mv = *(const float2*)&mr[s & 1][2 * g];
                GATEX(mv.x, mv.y, m5, m6, bb, cA, hA)
                hb2[(s + 1) & 1][64 * g + l] = hA;
                outb[(size_t)s * NH + r] = hA;   // fire-and-forget
            }
            wg_barrier();
        }
        hn[(size_t)NB * NH + (size_t)b * NH + r] = hA;
        cn[(size_t)NB * NH + (size_t)b * NH + r] = cA;
    }
}

extern "C" void kernel_launch(void* const* d_in, const int* in_sizes, int n_in,
                              void* d_out, int out_size, void* d_ws, size_t ws_size,
                              hipStream_t stream) {
    const float* x = (const float*)d_in[0];
    const float* h0 = (const float*)d_in[1];
    const float* c0 = (const float*)d_in[2];
    const float* W11 = (const float*)d_in[3];
    const float* W12 = (const float*)d_in[4];
    const float* U11 = (const float*)d_in[5];
    const float* U12 = (const float*)d_in[6];
    const float* dW11 = (const float*)d_in[7];
    const float* dW12 = (const float*)d_in[8];
    const float* dU11 = (const float*)d_in[9];
    const float* dU12 = (const float*)d_in[10];
    const float* b11 = (const float*)d_in[11];
    const float* b12 = (const float*)d_in[12];
    const float* W21 = (const float*)d_in[13];
    const float* W22 = (const float*)d_in[14];
    const float* U21 = (const float*)d_in[15];
    const float* U22 = (const float*)d_in[16];
    const float* dW21 = (const float*)d_in[17];
    const float* dW22 = (const float*)d_in[18];
    const float* dU21 = (const float*)d_in[19];
    const float* dU22 = (const float*)d_in[20];
    const float* b21 = (const float*)d_in[21];
    const float* b22 = (const float*)d_in[22];

    float* PT = (float*)d_ws;   // 2 MB
    float* out = (float*)d_out;

    hipLaunchKernelGGL(precomp_kernel, dim3(NB * NS), dim3(64), 0, stream,
                       x, W12, dW12, PT);
    hipLaunchKernelGGL(lstm_fused_kernel, dim3(NB), dim3(1024), 0, stream,
                       PT, h0, c0,
                       W11, U11, dW11, dU11, U12, dU12, b11, b12,
                       W21, U21, dW21, dU21, W22, dW22, U22, dU22, b21, b22,
                       out);
}